// Round 12
// baseline (219.750 us; speedup 1.0000x reference)
//
#include <hip/hip_runtime.h>
#include <math.h>

#define H    128
#define TT   128
#define CH   8            // main chunk size; tail tapers 4,2,1,1

// ws float offsets
#define OFF_H1V   0                 // [b][t][256]  h1 | v      : 262144 floats
#define OFF_PARTS 262144            // [b][t][1024] z2 | ad     : 1048576 floats
#define OFF_CNT   1441792           // int counters (poisoned 0xAA -> negative)

typedef __attribute__((ext_vector_type(2))) float f2;

// raw v_rcp_f32 (~1 ulp) instead of Newton-refined divide: shorter serial chain
__device__ __forceinline__ float rcpf(float x) { return __builtin_amdgcn_rcpf(x); }
__device__ __forceinline__ float sigf(float x)       { return rcpf(1.0f + __expf(-x)); }
__device__ __forceinline__ float tanhf_fast(float x) { return 1.0f - 2.0f * rcpf(1.0f + __expf(2.0f * x)); }

// sum over the 4-lane p-group via DPP quad_perm (VALU, no LDS traffic)
__device__ __forceinline__ float quad_sum(float v) {
    int t = __builtin_amdgcn_update_dpp(0, __float_as_int(v), 0xB1, 0xF, 0xF, true); // xor 1
    v += __int_as_float(t);
    t = __builtin_amdgcn_update_dpp(0, __float_as_int(v), 0x4E, 0xF, 0xF, true);     // xor 2
    v += __int_as_float(t);
    return v;
}

// Cheap spin: RELAXED polls, then ONE acquire load for the synchronizes-with edge.
__device__ __forceinline__ void wait_ge(int* ptr, int val) {
    while (__hip_atomic_load(ptr, __ATOMIC_RELAXED, __HIP_MEMORY_SCOPE_AGENT) < val)
        __builtin_amdgcn_s_sleep(1);
    (void)__hip_atomic_load(ptr, __ATOMIC_ACQUIRE, __HIP_MEMORY_SCOPE_AGENT);
}

// Per-step barrier: LDS-only drain (global stores stay in flight until chunk end).
#define BARRIER_LGKM() do { \
    asm volatile("s_waitcnt lgkmcnt(0)" ::: "memory"); \
    __builtin_amdgcn_s_barrier(); \
    asm volatile("" ::: "memory"); \
} while (0)

// Flag barrier: full drain so r0's agent-scope release publishes all waves'
// stores. With deferred flags the drained stores were issued a step earlier.
#define BARRIER_ALL() do { \
    asm volatile("s_waitcnt vmcnt(0) lgkmcnt(0)" ::: "memory"); \
    __builtin_amdgcn_s_barrier(); \
    asm volatile("" ::: "memory"); \
} while (0)

// Load one float4 of weights as two packed f2 pairs, pinned in the reg file.
#define DECLW4(nm, src) \
    float4 _t_##nm = (src); \
    f2 nm##_a = {_t_##nm.x, _t_##nm.y}; \
    f2 nm##_b = {_t_##nm.z, _t_##nm.w}; \
    asm volatile("" : "+v"(nm##_a), "+v"(nm##_b));

// Gate-aligned weight residency: thread (rg,p) holds rows {rg,rg+128,rg+256,rg+384},
// k-slice [32p, 32p+32) -> 128 floats/thread as 64 f2 pairs.
#define LOADW_ALL(W) \
    const float4* wpa_ = (const float4*)((W) + (size_t)(rg)       * H + p * 32); \
    const float4* wpb_ = (const float4*)((W) + (size_t)(rg + 128) * H + p * 32); \
    const float4* wpc_ = (const float4*)((W) + (size_t)(rg + 256) * H + p * 32); \
    const float4* wpd_ = (const float4*)((W) + (size_t)(rg + 384) * H + p * 32); \
    DECLW4(wa0, wpa_[0]) DECLW4(wa1, wpa_[1]) DECLW4(wa2, wpa_[2]) DECLW4(wa3, wpa_[3]) \
    DECLW4(wa4, wpa_[4]) DECLW4(wa5, wpa_[5]) DECLW4(wa6, wpa_[6]) DECLW4(wa7, wpa_[7]) \
    DECLW4(wb0, wpb_[0]) DECLW4(wb1, wpb_[1]) DECLW4(wb2, wpb_[2]) DECLW4(wb3, wpb_[3]) \
    DECLW4(wb4, wpb_[4]) DECLW4(wb5, wpb_[5]) DECLW4(wb6, wpb_[6]) DECLW4(wb7, wpb_[7]) \
    DECLW4(wc0, wpc_[0]) DECLW4(wc1, wpc_[1]) DECLW4(wc2, wpc_[2]) DECLW4(wc3, wpc_[3]) \
    DECLW4(wc4, wpc_[4]) DECLW4(wc5, wpc_[5]) DECLW4(wc6, wpc_[6]) DECLW4(wc7, wpc_[7]) \
    DECLW4(wd0, wpd_[0]) DECLW4(wd1, wpd_[1]) DECLW4(wd2, wpd_[2]) DECLW4(wd3, wpd_[3]) \
    DECLW4(wd4, wpd_[4]) DECLW4(wd5, wpd_[5]) DECLW4(wd6, wpd_[6]) DECLW4(wd7, wpd_[7])

// Packed dual-FMA: acc(lo,hi) += w(lo,hi) * h(lo,hi).
#define PKFMA(acc, w, h) \
    asm("v_pk_fma_f32 %0, %1, %2, %0" : "+v"(acc) : "v"(w), "v"(h));

#define FMA1(nm, hA, hB, acc) PKFMA(acc, nm##_a, hA) PKFMA(acc, nm##_b, hB)

#define DOTJ(j) { \
    f2 hA_ = {hv##j.x, hv##j.y}; f2 hB_ = {hv##j.z, hv##j.w}; \
    FMA1(wa##j, hA_, hB_, q0) FMA1(wb##j, hA_, hB_, q1) \
    FMA1(wc##j, hA_, hB_, q2) FMA1(wd##j, hA_, hB_, q3) }

// 8 b128 broadcast reads + 64 pk_fma + quad reduction -> a0..a3 = full gate dots
#define DOT_BODY(HBASE) \
    const float4* _hp4 = (const float4*)(HBASE); \
    float4 hv0=_hp4[0],hv1=_hp4[1],hv2=_hp4[2],hv3=_hp4[3], \
           hv4=_hp4[4],hv5=_hp4[5],hv6=_hp4[6],hv7=_hp4[7]; \
    f2 q0={0.f,0.f},q1={0.f,0.f},q2={0.f,0.f},q3={0.f,0.f}; \
    DOTJ(0) DOTJ(1) DOTJ(2) DOTJ(3) DOTJ(4) DOTJ(5) DOTJ(6) DOTJ(7) \
    float a0=q0.x+q0.y, a1=q1.x+q1.y, a2=q2.x+q2.y, a3=q3.x+q3.y; \
    a0 = quad_sum(a0); a1 = quad_sum(a1); a2 = quad_sum(a2); a3 = quad_sum(a3);

// ---------------------------------------------------------------------------
// B round: stage clen steps of (h1|v), project through w_ih1, publish flag.
// ---------------------------------------------------------------------------
#define B_ROUND(cstart, clen) { \
    if (r == 0) wait_ge(cntA, (cstart) + (clen)); \
    __syncthreads(); \
    if (r < (clen) * 32) { \
        int tl = r >> 5, k4 = r & 31, s = k4 >> 3, j = k4 & 7; \
        float4 v = *(const float4*)(hsrc + (size_t)((cstart) + tl) * 256 + k4 * 4); \
        *(float4*)&hb[(tl * 4 + s) * 36 + j * 4] = v; \
    } \
    __syncthreads(); \
    _Pragma("unroll") \
    for (int tl = 0; tl < (clen); tl++) { \
        DOT_BODY(hb + (tl * 4 + p) * 36) \
        float sel = (p == 0) ? a0 : (p == 1) ? a1 : (p == 2) ? a2 : a3; \
        pbase[(size_t)((cstart) + tl) * 1024 + r] = sel; \
    } \
    BARRIER_ALL(); \
    if (r == 0) \
        __hip_atomic_store(myCnt, (cstart) + (clen), __ATOMIC_RELEASE, __HIP_MEMORY_SCOPE_AGENT); }

// ---------------------------------------------------------------------------
// C helpers: reduce a finished gbuf buffer (waves 0..plen-1) and scatter its
// diagonals. Used overlapped with the next round's flag spin.
// ---------------------------------------------------------------------------
#define C_REDUCE(pbuf, plen) { \
    const int w_ = r >> 6, l_ = r & 63; \
    if (w_ < (plen)) { \
        float v_ = gbuf[pbuf][w_][l_] + gbuf[pbuf][w_][l_ + 64]; \
        v_ = quad_sum(v_); \
        v_ += __shfl_xor(v_, 4, 64);  v_ += __shfl_xor(v_, 8, 64); \
        v_ += __shfl_xor(v_, 16, 64); v_ += __shfl_xor(v_, 32, 64); \
        if (l_ == 0) scr[w_] = v_; \
    } }

#define C_SCATTER(pstart, plen) \
    if (r < (plen) * 32) { \
        const int tl_ = r >> 5, d_ = r & 31; \
        outp[(size_t)(b * TT + (pstart) + tl_) * 1024 + d_ * 33] = scr[tl_]; \
    }

// Derivative block (pure function of saved gate state) -> gbuf write.
#define C_DH2(IDX, GI, GF, GG, GO, TH, C2O, BUF) { \
    float di_ = (GI) * (1.f - (GI)) * af[IDX].x, df_ = (GF) * (1.f - (GF)) * af[IDX].y; \
    float dg_ = (1.f - (GG) * (GG)) * af[IDX].z, dd_ = (GO) * (1.f - (GO)) * af[IDX].w; \
    float dc_ = df_ * (C2O) + di_ * (GG) + (GI) * dg_; \
    float dh2_ = dd_ * (TH) + (GO) * (1.f - (TH) * (TH)) * dc_; \
    if (p == 0) gbuf[BUF][IDX][rg] = wo * dh2_; }

// C round: spin (lanes 448/449) || reduce prev gbuf; sync; scatter prev;
// prefetch; clen recurrence steps into gbuf[cbuf]. The derivative block of
// step tl is DEFERRED to step tl+1's top (overlaps its ds_reads); the round's
// last step computes it immediately so gbuf completes before the round ends.
#define C_ROUND(cstart, clen, cbuf, pstart, plen, pbuf, HASPREV) { \
    if (r == 448) wait_ge(cntB1, (cstart) + (clen)); \
    if (r == 449) wait_ge(cntB2, (cstart) + (clen)); \
    if (HASPREV) { C_REDUCE(pbuf, plen) } \
    __syncthreads(); \
    if (HASPREV) { C_SCATTER(pstart, plen) } \
    float4 zf[CH], af[CH]; \
    _Pragma("unroll") \
    for (int tl = 0; tl < (clen); tl++) { \
        zf[tl] = *(const float4*)(parts + (size_t)((cstart) + tl) * 1024 + rg * 4); \
        af[tl] = *(const float4*)(parts + (size_t)((cstart) + tl) * 1024 + 512 + rg * 4); \
    } \
    _Pragma("unroll") \
    for (int tl = 0; tl < (clen); tl++) { \
        const int t = (cstart) + tl; \
        if (tl > 0) { C_DH2(tl - 1, gi_s, gf_s, gg_s, go_s, th_s, c2o_s, cbuf) } \
        const float* hc = hbuf[t & 1]; \
        float* hx = hbuf[(t & 1) ^ 1]; \
        DOT_BODY(hc + p * 36) \
        float z0 = a0 + b0 + zf[tl].x; \
        float z1 = a1 + b1 + zf[tl].y; \
        float z2 = a2 + b2 + zf[tl].z; \
        float z3 = a3 + b3 + zf[tl].w; \
        float gi = sigf(z0), gf = sigf(z1), gg = tanhf_fast(z2), go = sigf(z3); \
        float c2o = c2; \
        c2 = gf * c2 + gi * gg; \
        float th = tanhf_fast(c2); \
        if (p == wsl) hx[p * 36 + wpos] = go * th; \
        gi_s = gi; gf_s = gf; gg_s = gg; go_s = go; th_s = th; c2o_s = c2o; \
        if (tl == (clen) - 1) { C_DH2(tl, gi, gf, gg, go, th, c2o, cbuf) } \
        BARRIER_LGKM(); \
    } }

// ---------------------------------------------------------------------------
// Overlapped 4-role pipeline, one CU per (role,batch): 32 blocks x 512 thr.
//   role 0 = A : layer-1 recurrence (w_hh0)        -> h1[t], v[t]
//   role 1 = B1: w_ih1 @ h1 (chunked)              -> parts[.., 0:512)
//   role 2 = B2: w_ih1 @ v  (chunked)              -> parts[.., 512:1024)
//   role 3 = C : w_hh1 @ h2 + elementwise -> DIAGONAL-only output scatter
// Output zeros are pre-written by hipMemsetAsync before this kernel.
// FULL TAPER: chunks 8x15, then 4,2,1,1 (flags at 120,124,126,127,128) —
// after A retires step 127, C has only 1 serial step + reduce left.
// ---------------------------------------------------------------------------
__global__ __launch_bounds__(512)
__attribute__((amdgpu_waves_per_eu(1, 2)))
void pipe_kernel(const float* __restrict__ x,
                 const float* __restrict__ w_ih0,
                 const float* __restrict__ w_hh0,
                 const float* __restrict__ b_ih0,
                 const float* __restrict__ b_hh0,
                 const float* __restrict__ w_ih1,
                 const float* __restrict__ w_hh1,
                 const float* __restrict__ b_ih1,
                 const float* __restrict__ b_hh1,
                 const float* __restrict__ w_out,
                 float* __restrict__ ws,
                 float* __restrict__ outp) {
    const int role = blockIdx.x >> 3;
    const int b    = blockIdx.x & 7;
    const int r    = threadIdx.x;
    const int rg   = r >> 2, p = r & 3;
    const int wsl  = rg >> 5, wpos = rg & 31;

    int* cntA  = (int*)ws + OFF_CNT       + b * 32;
    int* cntB1 = (int*)ws + OFF_CNT + 256 + b * 32;
    int* cntB2 = (int*)ws + OFF_CNT + 512 + b * 32;
    float* h1v = ws + OFF_H1V + (size_t)b * TT * 256;

    __shared__ float hbuf[2][144];    // recurrent state, 4 padded slices x 36
    __shared__ float u_s[TT];
    __shared__ float scr[512];
    __shared__ float hb[CH * 144];    // B chunk staging
    __shared__ float gbuf[2][CH][128]; // C: double-buffered unreduced g

    if (role == 0) {
        // ===================== Stage A: layer-1 recurrence =====================
        LOADW_ALL(w_hh0)
        const float b0 = b_ih0[rg]       + b_hh0[rg];
        const float b1 = b_ih0[rg + 128] + b_hh0[rg + 128];
        const float b2 = b_ih0[rg + 256] + b_hh0[rg + 256];
        const float b3 = b_ih0[rg + 384] + b_hh0[rg + 384];
        const float wi0 = w_ih0[rg], wi1 = w_ih0[rg + 128];
        const float wi2 = w_ih0[rg + 256], wi3 = w_ih0[rg + 384];
        {   // u[t] = trace(x[b,t]) cooperatively (4 partials per t)
            const float* xb = x + (size_t)(b * TT + (r & 127)) * 1024;
            const int pq = r >> 7;
            float u = 0.f;
#pragma unroll
            for (int i = 0; i < 8; i++) u += xb[(pq * 8 + i) * 33];
            scr[r] = u;
        }
        if (r < 144) hbuf[0][r] = 0.f;
        __syncthreads();
        if (r < TT) u_s[r] = scr[r] + scr[r + 128] + scr[r + 256] + scr[r + 384];
        __syncthreads();

        float c1 = 0.f;
        float hn_prev = 0.f;
        // saved state for the DEFERRED derivative block of step t-1
        float gi_s = 0.f, gf_s = 0.f, gg_s = 0.f, go_s = 0.f, th_s = 0.f, c1o_s = 0.f;
        for (int t = 0; t < TT; t++) {
            // publish step t-1: hn saved; vn computed HERE (off the serial
            // chain — overlaps this step's ds_read phase on the VALU pipe)
            if (t > 0) {
                float di = gi_s * (1.f - gi_s) * wi0, df = gf_s * (1.f - gf_s) * wi1;
                float dg = (1.f - gg_s * gg_s) * wi2, dd = go_s * (1.f - go_s) * wi3;
                float dc = df * c1o_s + di * gg_s + gi_s * dg;
                float vn = dd * th_s + go_s * (1.f - th_s * th_s) * dc;
                if (p == 0) h1v[(t - 1) * 256 + rg] = hn_prev;
                if (p == 1) h1v[(t - 1) * 256 + 128 + rg] = vn;
            }
            const float u = u_s[t];
            const float* hc = hbuf[t & 1];
            float* hx = hbuf[(t & 1) ^ 1];
            DOT_BODY(hc + p * 36)
            float z0 = a0 + fmaf(wi0, u, b0);
            float z1 = a1 + fmaf(wi1, u, b1);
            float z2 = a2 + fmaf(wi2, u, b2);
            float z3 = a3 + fmaf(wi3, u, b3);
            float gi = sigf(z0), gf = sigf(z1), gg = tanhf_fast(z2), go = sigf(z3);
            float c1o = c1;
            c1 = gf * c1 + gi * gg;
            float th = tanhf_fast(c1);
            float hn = go * th;
            if (p == wsl) hx[p * 36 + wpos] = hn;       // one writer per h-index
            hn_prev = hn;
            gi_s = gi; gf_s = gf; gg_s = gg; go_s = go; th_s = th; c1o_s = c1o;
            if (t > 0 && ((t & (CH - 1)) == 0 || t == 124 || t == 126 || t == 127)) {
                // deferred flag: the prior chunk's last store was issued at
                // the TOP of this step -> vmcnt(0) here is ~free.
                BARRIER_ALL();
                if (r == 0)
                    __hip_atomic_store(cntA, t, __ATOMIC_RELEASE, __HIP_MEMORY_SCOPE_AGENT);
            } else {
                BARRIER_LGKM();  // LDS recurrence state only — no vmcnt drain
            }
        }
        // epilogue: publish final step (deferred vn), drain, release final flag
        {
            float di = gi_s * (1.f - gi_s) * wi0, df = gf_s * (1.f - gf_s) * wi1;
            float dg = (1.f - gg_s * gg_s) * wi2, dd = go_s * (1.f - go_s) * wi3;
            float dc = df * c1o_s + di * gg_s + gi_s * dg;
            float vn = dd * th_s + go_s * (1.f - th_s * th_s) * dc;
            if (p == 0) h1v[(TT - 1) * 256 + rg] = hn_prev;
            if (p == 1) h1v[(TT - 1) * 256 + 128 + rg] = vn;
        }
        BARRIER_ALL();
        if (r == 0)
            __hip_atomic_store(cntA, TT, __ATOMIC_RELEASE, __HIP_MEMORY_SCOPE_AGENT);
    } else if (role == 1 || role == 2) {
        // ============ Stages B1/B2: w_ih1 @ (h1 | v), chunk-parallel ============
        LOADW_ALL(w_ih1)
        int* myCnt = (role == 2) ? cntB2 : cntB1;
        const float* hsrc = h1v + ((role == 2) ? 128 : 0);
        float* pbase = ws + OFF_PARTS + (size_t)b * TT * 1024 + ((role == 2) ? 512 : 0);
        for (int c = 0; c < 15; c++) { B_ROUND(c * CH, CH) }
        B_ROUND(120, 4)
        B_ROUND(124, 2)
        B_ROUND(126, 1)
        B_ROUND(127, 1)
    } else {
        // ==== Stage C: w_hh1 @ h2 + layer-2 elementwise + diag-only scatter ====
        LOADW_ALL(w_hh1)
        const float b0 = b_ih1[rg]       + b_hh1[rg];
        const float b1 = b_ih1[rg + 128] + b_hh1[rg + 128];
        const float b2 = b_ih1[rg + 256] + b_hh1[rg + 256];
        const float b3 = b_ih1[rg + 384] + b_hh1[rg + 384];
        const float wo = w_out[rg];
        if (r < 144) hbuf[0][r] = 0.f;
        __syncthreads();
        const float* parts = ws + OFF_PARTS + (size_t)b * TT * 1024;
        float c2 = 0.f;
        float gi_s = 0.f, gf_s = 0.f, gg_s = 0.f, go_s = 0.f, th_s = 0.f, c2o_s = 0.f;
        // round 0 (no prev)
        C_ROUND(0, CH, 0, 0, 0, 0, 0)
        // rounds 1..14 (prev = round c-1, len 8)
        for (int c = 1; c < 15; c++) {
            C_ROUND(c * CH, CH, c & 1, (c - 1) * CH, CH, (c - 1) & 1, 1)
        }
        // tapered tail: 4, 2, 1, 1
        C_ROUND(120, 4, 1, 112, CH, 0, 1)
        C_ROUND(124, 2, 0, 120, 4, 1, 1)
        C_ROUND(126, 1, 1, 124, 2, 0, 1)
        C_ROUND(127, 1, 0, 126, 1, 1, 1)
        // final: reduce + scatter the last round (buf 0, len 1, t=127)
        {
            C_REDUCE(0, 1)
            BARRIER_LGKM();
            C_SCATTER(127, 1)
        }
    }
}

extern "C" void kernel_launch(void* const* d_in, const int* in_sizes, int n_in,
                              void* d_out, int out_size, void* d_ws, size_t ws_size,
                              hipStream_t stream) {
    const float* x     = (const float*)d_in[0];
    const float* w_ih0 = (const float*)d_in[1];
    const float* w_hh0 = (const float*)d_in[2];
    const float* b_ih0 = (const float*)d_in[3];
    const float* b_hh0 = (const float*)d_in[4];
    const float* w_ih1 = (const float*)d_in[5];
    const float* w_hh1 = (const float*)d_in[6];
    const float* b_ih1 = (const float*)d_in[7];
    const float* b_hh1 = (const float*)d_in[8];
    const float* w_out = (const float*)d_in[9];
    // d_in[10] = b_out: constant offset, zero derivative -> unused

    float* ws = (float*)d_ws;   // counters rely on 0xAA poison (<0 as int)

    // Zero the output (31/32 of it stays zero; pipe_kernel scatters diagonals).
    hipMemsetAsync(d_out, 0, (size_t)out_size, stream);

    pipe_kernel<<<dim3(32), dim3(512), 0, stream>>>(x, w_ih0, w_hh0, b_ih0, b_hh0,
                                                    w_ih1, w_hh1, b_ih1, b_hh1, w_out,
                                                    ws, (float*)d_out);
}